// Round 1
// baseline (1826.257 us; speedup 1.0000x reference)
//
#include <hip/hip_runtime.h>
#include <hip/hip_bf16.h>

// ---------------------------------------------------------------------------
// DeepDCNN: emb-gather -> 4x [grouped full-conv + pair-fold + ordered top-k +
// tanh] -> FC.  All fp32.
//
// Layer dims:
//  L1: in (64, 64,1024) IPG=1  NF=10 K=7 -> fold (64,320,1030) -> keep 768
//  L2: in (64,320, 768) IPG=10 NF=14 K=5 -> fold (64,224, 772) -> keep 512
//  L3: in (64,224, 512) IPG=14 NF=18 K=5 -> fold (64,144, 516) -> keep 256
//  L4: in (64,144, 256) IPG=18 NF=22 K=3 -> fold (64, 88, 258) -> keep 4
//  FC: (64,352) @ (6,352)^T + b -> (64,6)
// ---------------------------------------------------------------------------

__device__ __forceinline__ unsigned f2ord(float f) {
    unsigned u = __float_as_uint(f);
    return (u & 0x80000000u) ? ~u : (u | 0x80000000u);
}

// Order-preserving top-k of row[0..n) (LDS) -> tanh -> out (global, k elems).
// Radix-select (4x8bit MSD) finds exact k-th-largest key T and tie budget,
// then stable prefix-sum compaction keeps earliest ties (matches stable
// lax.top_k + sorted-index gather). blockDim must be 256.
__device__ void topk_tanh_write(const float* row, int n, int k,
                                float* __restrict__ out,
                                int* hist, int* sA, int* sB, int* bc)
{
    const int t = threadIdx.x;
    const int bs = 256;

    unsigned prefix = 0;
    int remaining = k;
    for (int shift = 24; shift >= 0; shift -= 8) {
        for (int i = t; i < 256; i += bs) hist[i] = 0;
        __syncthreads();
        const unsigned himask = (shift == 24) ? 0u : (0xFFFFFFFFu << (shift + 8));
        for (int i = t; i < n; i += bs) {
            unsigned key = f2ord(row[i]);
            if ((key & himask) == prefix)
                atomicAdd(&hist[(key >> shift) & 255u], 1);
        }
        __syncthreads();
        if (t == 0) {
            int cum = 0;
            int bin = 255;
            for (;; --bin) {
                cum += hist[bin];
                if (cum >= remaining || bin == 0) break;
            }
            bc[0] = (int)(prefix | ((unsigned)bin << shift));
            bc[1] = remaining - (cum - hist[bin]);
        }
        __syncthreads();
        prefix    = (unsigned)bc[0];
        remaining = bc[1];
        __syncthreads();
    }
    const unsigned T = prefix;       // exact key of k-th largest
    const int needTies = remaining;  // # of ==T elements to keep (earliest)

    // stable compaction: chunked counts + workgroup scan
    const int CH = (n + bs - 1) / bs;
    int beg = t * CH; if (beg > n) beg = n;
    int end = beg + CH; if (end > n) end = n;

    int gcnt = 0, ecnt = 0;
    for (int i = beg; i < end; ++i) {
        unsigned key = f2ord(row[i]);
        gcnt += (key > T);
        ecnt += (key == T);
    }
    sA[t] = gcnt; sB[t] = ecnt;
    __syncthreads();
    for (int off = 1; off < bs; off <<= 1) {
        int a = 0, b2 = 0;
        if (t >= off) { a = sA[t - off]; b2 = sB[t - off]; }
        __syncthreads();
        sA[t] += a; sB[t] += b2;
        __syncthreads();
    }
    const int gtBefore = sA[t] - gcnt;
    const int eqBefore = sB[t] - ecnt;

    int gRun = 0, eRun = 0;
    for (int i = beg; i < end; ++i) {
        unsigned key = f2ord(row[i]);
        if (key > T) {
            int keptEqBefore = eqBefore + eRun;
            if (keptEqBefore > needTies) keptEqBefore = needTies;
            out[gtBefore + gRun + keptEqBefore] = tanhf(row[i]);
            ++gRun;
        } else if (key == T) {
            int eIdx = eqBefore + eRun;
            if (eIdx < needTies)
                out[gtBefore + gRun + eIdx] = tanhf(row[i]);
            ++eRun;
        }
    }
    __syncthreads();
}

// ---------------------------------------------------------------------------
// Layer 1 fused: emb gather + depth-pair conv (IPG=1) + fold + select + tanh.
// grid (32 j, 64 b), block 256.
// ---------------------------------------------------------------------------
__global__ __launch_bounds__(256) void layer1_fused(
    const int* __restrict__ tokens, const float* __restrict__ emb,
    const float* __restrict__ W1, const float* __restrict__ B1,
    float* __restrict__ Z1)
{
    const int j = blockIdx.x;   // 0..31 (pair-group)
    const int b = blockIdx.y;   // 0..63
    const int t = threadIdx.x;

    __shared__ float xr[2][1036];   // padded input rows 2j, 2j+1
    __shared__ float row[1030];
    __shared__ float wA[10][7], wB[10][7];
    __shared__ float bsum[10];
    __shared__ int hist[256], sA[256], sB[256], bc[2];

    const float2* emb2 = (const float2*)emb;
    for (int i = t; i < 1036; i += 256) {
        int s = i - 6;
        float a = 0.f, c = 0.f;
        if (s >= 0 && s < 1024) {
            int tok = tokens[b * 1024 + s];
            float2 v = emb2[(size_t)tok * 32 + j];
            a = v.x; c = v.y;
        }
        xr[0][i] = a;
        xr[1][i] = c;
    }
    if (t < 70) {
        wA[t / 7][t % 7] = W1[(2 * j * 10) * 7 + t];
        wB[t / 7][t % 7] = W1[((2 * j + 1) * 10) * 7 + t];
    }
    if (t < 10) bsum[t] = B1[2 * j * 10 + t] + B1[(2 * j + 1) * 10 + t];
    __syncthreads();

    for (int f = 0; f < 10; ++f) {
        for (int s = t; s < 1030; s += 256) {
            float acc = bsum[f];
            #pragma unroll
            for (int k = 0; k < 7; ++k)
                acc += xr[0][s + k] * wA[f][k] + xr[1][s + k] * wB[f][k];
            row[s] = acc;
        }
        __syncthreads();
        topk_tanh_write(row, 1030, 768,
                        Z1 + ((size_t)(b * 320 + j * 10 + f)) * 768,
                        hist, sA, sB, bc);
        __syncthreads();
    }
}

// ---------------------------------------------------------------------------
// Generic grouped conv + fold (layers 2-4).
// grid (s-tiles, G/2, B), block 256 = TILE.
// Y[b, j*NF+f, s] = sum_{h,c,k} X[b, (2j+h)*IPG+c, s-(K-1)+k] * W[...] + bias2
// ---------------------------------------------------------------------------
template <int IPG, int NF, int K, int TILE>
__global__ __launch_bounds__(256) void conv_fold_kernel(
    const float* __restrict__ X, const float* __restrict__ W,
    const float* __restrict__ Bias, float* __restrict__ Y,
    int Cin, int S, int Sout, int Cfold)
{
    const int t  = threadIdx.x;
    const int s0 = blockIdx.x * TILE;
    const int j  = blockIdx.y;
    const int b  = blockIdx.z;

    constexpr int WIDTH = TILE + K - 1;
    __shared__ float xs[2 * IPG][WIDTH];
    __shared__ float wt[2 * NF * IPG * K];
    __shared__ float bsum[NF];

    const float* Xb = X + ((size_t)b * Cin + (size_t)(2 * j) * IPG) * S;
    for (int idx = t; idx < 2 * IPG * WIDTH; idx += 256) {
        int r = idx / WIDTH, p = idx % WIDTH;
        int sg = s0 + p - (K - 1);
        xs[r][p] = (sg >= 0 && sg < S) ? Xb[(size_t)r * S + sg] : 0.f;
    }
    const float* Wb = W + (size_t)(2 * j * NF) * IPG * K;
    for (int idx = t; idx < 2 * NF * IPG * K; idx += 256) wt[idx] = Wb[idx];
    if (t < NF) bsum[t] = Bias[2 * j * NF + t] + Bias[(2 * j + 1) * NF + t];
    __syncthreads();

    const int s = s0 + t;
    if (s < Sout) {
        for (int f = 0; f < NF; ++f) {
            float acc = bsum[f];
            #pragma unroll
            for (int h = 0; h < 2; ++h) {
                const float* wr = &wt[(h * NF + f) * IPG * K];
                #pragma unroll
                for (int c = 0; c < IPG; ++c) {
                    #pragma unroll
                    for (int k = 0; k < K; ++k)
                        acc += xs[h * IPG + c][t + k] * wr[c * K + k];
                }
            }
            Y[((size_t)b * Cfold + j * NF + f) * (size_t)Sout + s] = acc;
        }
    }
}

// ---------------------------------------------------------------------------
// Standalone per-row top-k select + tanh. One block per row, block 256.
// ---------------------------------------------------------------------------
__global__ __launch_bounds__(256) void select_kernel(
    const float* __restrict__ Y, float* __restrict__ Z, int n, int k)
{
    __shared__ float row[1032];
    __shared__ int hist[256], sA[256], sB[256], bc[2];
    const int r = blockIdx.x;
    const float* src = Y + (size_t)r * n;
    for (int i = threadIdx.x; i < n; i += 256) row[i] = src[i];
    __syncthreads();
    topk_tanh_write(row, n, k, Z + (size_t)r * k, hist, sA, sB, bc);
}

// ---------------------------------------------------------------------------
// FC: (64,352) @ (6,352)^T + b
// ---------------------------------------------------------------------------
__global__ __launch_bounds__(192) void fc_kernel(
    const float* __restrict__ Z, const float* __restrict__ Wf,
    const float* __restrict__ bf, float* __restrict__ out)
{
    int g = blockIdx.x * blockDim.x + threadIdx.x;
    if (g >= 64 * 6) return;
    int b = g / 6, c = g % 6;
    float acc = bf[c];
    const float* zr = Z + b * 352;
    const float* wr = Wf + c * 352;
    for (int i = 0; i < 352; ++i) acc += zr[i] * wr[i];
    out[g] = acc;
}

extern "C" void kernel_launch(void* const* d_in, const int* in_sizes, int n_in,
                              void* d_out, int out_size, void* d_ws, size_t ws_size,
                              hipStream_t stream)
{
    const int*   tokens = (const int*)  d_in[0];
    const float* emb    = (const float*)d_in[1];
    const float* w1     = (const float*)d_in[2];
    const float* b1     = (const float*)d_in[3];
    const float* w2     = (const float*)d_in[4];
    const float* b2     = (const float*)d_in[5];
    const float* w3     = (const float*)d_in[6];
    const float* b3     = (const float*)d_in[7];
    const float* w4     = (const float*)d_in[8];
    const float* b4     = (const float*)d_in[9];
    const float* fcw    = (const float*)d_in[10];
    const float* fcb    = (const float*)d_in[11];
    float* out = (float*)d_out;
    float* ws  = (float*)d_ws;

    // workspace layout (floats), buffers reused once dead:
    //  Z1 [0,        15728640)   64*320*768
    //  Y2 [15728640, 26796032)   64*224*772   (peak ~107 MB)
    //  Z2 [0,         7340032)   64*224*512
    //  Y3 [7340032,  12095488)   64*144*516
    //  Z3 [0,         2359296)   64*144*256
    //  Y4 [2359296,   3812352)   64*88*258
    //  Z4 [3812352,   3834880)   64*88*4
    float* Z1 = ws;
    float* Y2 = ws + 15728640;
    float* Z2 = ws;
    float* Y3 = ws + 7340032;
    float* Z3 = ws;
    float* Y4 = ws + 2359296;
    float* Z4 = ws + 3812352;

    layer1_fused<<<dim3(32, 64), 256, 0, stream>>>(tokens, emb, w1, b1, Z1);

    conv_fold_kernel<10, 14, 5, 256><<<dim3(4, 16, 64), 256, 0, stream>>>(
        Z1, w2, b2, Y2, 320, 768, 772, 224);
    select_kernel<<<64 * 224, 256, 0, stream>>>(Y2, Z2, 772, 512);

    conv_fold_kernel<14, 18, 5, 256><<<dim3(3, 8, 64), 256, 0, stream>>>(
        Z2, w3, b3, Y3, 224, 512, 516, 144);
    select_kernel<<<64 * 144, 256, 0, stream>>>(Y3, Z3, 516, 256);

    conv_fold_kernel<18, 22, 3, 256><<<dim3(2, 4, 64), 256, 0, stream>>>(
        Z3, w4, b4, Y4, 144, 256, 258, 88);
    select_kernel<<<64 * 88, 256, 0, stream>>>(Y4, Z4, 258, 4);

    fc_kernel<<<2, 192, 0, stream>>>(Z4, fcw, fcb, out);
}

// Round 2
// 680.365 us; speedup vs baseline: 2.6842x; 2.6842x over previous
//
#include <hip/hip_runtime.h>
#include <hip/hip_bf16.h>
#include <math.h>

// ---------------------------------------------------------------------------
// DeepDCNN: emb-gather -> 4x [grouped full-conv + pair-fold + ordered top-k +
// tanh] -> FC.  All fp32.  Top-k is wave-level (no __syncthreads, no serial
// bin scan): radix-select over register-held chunks + wave-private LDS hist.
// ---------------------------------------------------------------------------

#define WAVE_FENCE() __asm__ volatile("s_waitcnt lgkmcnt(0)" ::: "memory")

__device__ __forceinline__ unsigned f2ord(float f) {
    unsigned u = __float_as_uint(f);
    return (u & 0x80000000u) ? ~u : (u | 0x80000000u);
}

// Wave-level exact top-k (order-preserving, stable ties = earliest kept),
// matching lax.top_k -> sort(idx) -> gather.  Lane holds the contiguous
// chunk [lane*CH, lane*CH+len) of the row in registers (keys/vals).
// hist = per-wave 256-int LDS scratch.  Writes tanh(kept) to out[0..k).
template<int CH>
__device__ void wave_select(const unsigned* keys, const float* vals,
                            int len, int k, int* hist,
                            float* __restrict__ out)
{
    const int lane = threadIdx.x & 63;
    unsigned prefix = 0;
    int remaining = k;
    #pragma unroll
    for (int shift = 24; shift >= 0; shift -= 8) {
        hist[lane] = 0; hist[lane + 64] = 0; hist[lane + 128] = 0; hist[lane + 192] = 0;
        WAVE_FENCE();
        const unsigned himask = (shift == 24) ? 0u : (0xFFFFFFFFu << (shift + 8));
        #pragma unroll
        for (int i = 0; i < CH; ++i) {
            if (i < len && (keys[i] & himask) == prefix)
                atomicAdd(&hist[(keys[i] >> shift) & 255u], 1);
        }
        WAVE_FENCE();
        int4 hv = *(const int4*)(hist + 4 * lane);
        int h0 = hv.x, h1 = hv.y, h2 = hv.z, h3 = hv.w;
        int s = h0 + h1 + h2 + h3;
        // wave suffix-sum: U = sum over lanes >= lane
        int U = s;
        #pragma unroll
        for (int off = 1; off < 64; off <<= 1) {
            int tmp = __shfl_down(U, off, 64);
            if (lane + off < 64) U += tmp;
        }
        int base = U - s;                 // sum over lanes > lane
        int S3 = base + h3;               // S(b) = sum_{b' >= b} hist[b']
        int S2 = S3 + h2;
        int S1 = S2 + h1;
        int S0 = S1 + h0;
        int cand = -1;                    // max bin with S(bin) >= remaining
        if      (S3 >= remaining) cand = 4 * lane + 3;
        else if (S2 >= remaining) cand = 4 * lane + 2;
        else if (S1 >= remaining) cand = 4 * lane + 1;
        else if (S0 >= remaining) cand = 4 * lane;
        #pragma unroll
        for (int off = 1; off < 64; off <<= 1)
            cand = max(cand, __shfl_xor(cand, off, 64));
        const int B = cand;               // wave-uniform selected bin
        const int bi = B & 3, owner = B >> 2;
        int SB_l = (bi == 3) ? S3 : (bi == 2) ? S2 : (bi == 1) ? S1 : S0;
        int hB_l = (bi == 3) ? h3 : (bi == 2) ? h2 : (bi == 1) ? h1 : h0;
        int SB = __shfl(SB_l, owner, 64);
        int hB = __shfl(hB_l, owner, 64);
        remaining -= (SB - hB);           // count strictly above bin B
        prefix |= ((unsigned)B) << shift;
    }
    const unsigned T = prefix;            // exact key of k-th largest
    const int needTies = remaining;       // # of ==T to keep (earliest)

    int g = 0, e = 0;
    #pragma unroll
    for (int i = 0; i < CH; ++i)
        if (i < len) { g += (keys[i] > T); e += (keys[i] == T); }
    int pg = g, pe = e;
    #pragma unroll
    for (int off = 1; off < 64; off <<= 1) {
        int tg = __shfl_up(pg, off, 64);
        int te = __shfl_up(pe, off, 64);
        if (lane >= off) { pg += tg; pe += te; }
    }
    const int gtBefore = pg - g, eqBefore = pe - e;
    int gRun = 0, eRun = 0;
    #pragma unroll
    for (int i = 0; i < CH; ++i) {
        if (i < len) {
            unsigned key = keys[i];
            if (key > T) {
                int cap = eqBefore + eRun; if (cap > needTies) cap = needTies;
                out[gtBefore + gRun + cap] = tanhf(vals[i]);
                ++gRun;
            } else if (key == T) {
                int eIdx = eqBefore + eRun;
                if (eIdx < needTies) out[gtBefore + gRun + eIdx] = tanhf(vals[i]);
                ++eRun;
            }
        }
    }
}

// ---------------------------------------------------------------------------
// Layer 1 fused: emb gather + pair conv (IPG=1,K=7) + fold + select + tanh.
// grid (32 j, 64 b), block 320 = 5 waves; wave w handles f = w, w+5.
// ---------------------------------------------------------------------------
__global__ __launch_bounds__(320) void layer1_fused(
    const int* __restrict__ tokens, const float* __restrict__ emb,
    const float* __restrict__ W1, const float* __restrict__ B1,
    float* __restrict__ Z1)
{
    const int j = blockIdx.x;   // 0..31 pair-group
    const int b = blockIdx.y;   // 0..63
    const int t = threadIdx.x;
    const int w = t >> 6, lane = t & 63;

    __shared__ float xr[2][1036];
    __shared__ __align__(16) int hist[5][256];

    const float2* emb2 = (const float2*)emb;
    for (int i = t; i < 1036; i += 320) {
        int s = i - 6;
        float a = 0.f, c = 0.f;
        if (s >= 0 && s < 1024) {
            int tok = tokens[b * 1024 + s];
            float2 v = emb2[(size_t)tok * 32 + j];
            a = v.x; c = v.y;
        }
        xr[0][i] = a;
        xr[1][i] = c;
    }
    __syncthreads();

    const int beg = lane * 17;
    const int len = max(0, min(17, 1030 - beg));
    float x0[23], x1[23];
    #pragma unroll
    for (int i = 0; i < 23; ++i)
        if (i < len + 6) { x0[i] = xr[0][beg + i]; x1[i] = xr[1][beg + i]; }

    for (int f = w; f < 10; f += 5) {
        float wa[7], wb[7];
        #pragma unroll
        for (int k2 = 0; k2 < 7; ++k2) {
            wa[k2] = W1[(2 * j * 10 + f) * 7 + k2];
            wb[k2] = W1[((2 * j + 1) * 10 + f) * 7 + k2];
        }
        float bias = B1[2 * j * 10 + f] + B1[(2 * j + 1) * 10 + f];
        float vals[17]; unsigned keys[17];
        #pragma unroll
        for (int i = 0; i < 17; ++i) {
            if (i < len) {
                float acc = bias;
                #pragma unroll
                for (int k2 = 0; k2 < 7; ++k2)
                    acc += x0[i + k2] * wa[k2] + x1[i + k2] * wb[k2];
                vals[i] = acc; keys[i] = f2ord(acc);
            }
        }
        wave_select<17>(keys, vals, len, 768, hist[w],
                        Z1 + ((size_t)(b * 320 + j * 10 + f)) * 768);
    }
}

// ---------------------------------------------------------------------------
// Generic grouped conv + fold (layers 2-4), unchanged (LDS-tiled).
// ---------------------------------------------------------------------------
template <int IPG, int NF, int K, int TILE>
__global__ __launch_bounds__(256) void conv_fold_kernel(
    const float* __restrict__ X, const float* __restrict__ W,
    const float* __restrict__ Bias, float* __restrict__ Y,
    int Cin, int S, int Sout, int Cfold)
{
    const int t  = threadIdx.x;
    const int s0 = blockIdx.x * TILE;
    const int j  = blockIdx.y;
    const int b  = blockIdx.z;

    constexpr int WIDTH = TILE + K - 1;
    __shared__ float xs[2 * IPG][WIDTH];
    __shared__ float wt[2 * NF * IPG * K];
    __shared__ float bsum[NF];

    const float* Xb = X + ((size_t)b * Cin + (size_t)(2 * j) * IPG) * S;
    for (int idx = t; idx < 2 * IPG * WIDTH; idx += 256) {
        int r = idx / WIDTH, p = idx % WIDTH;
        int sg = s0 + p - (K - 1);
        xs[r][p] = (sg >= 0 && sg < S) ? Xb[(size_t)r * S + sg] : 0.f;
    }
    const float* Wb = W + (size_t)(2 * j * NF) * IPG * K;
    for (int idx = t; idx < 2 * NF * IPG * K; idx += 256) wt[idx] = Wb[idx];
    if (t < NF) bsum[t] = Bias[2 * j * NF + t] + Bias[(2 * j + 1) * NF + t];
    __syncthreads();

    const int s = s0 + t;
    if (s < Sout) {
        for (int f = 0; f < NF; ++f) {
            float acc = bsum[f];
            #pragma unroll
            for (int h = 0; h < 2; ++h) {
                const float* wr = &wt[(h * NF + f) * IPG * K];
                #pragma unroll
                for (int c = 0; c < IPG; ++c) {
                    #pragma unroll
                    for (int k = 0; k < K; ++k)
                        acc += xs[h * IPG + c][t + k] * wr[c * K + k];
                }
            }
            Y[((size_t)b * Cfold + j * NF + f) * (size_t)Sout + s] = acc;
        }
    }
}

// ---------------------------------------------------------------------------
// Wave-per-row select + tanh.  block 256 = 4 waves = 4 rows.
// ---------------------------------------------------------------------------
template<int CH>
__global__ __launch_bounds__(256) void select_kernel(
    const float* __restrict__ Y, float* __restrict__ Z, int n, int k)
{
    __shared__ __align__(16) int hist[4][256];
    const int w = threadIdx.x >> 6, lane = threadIdx.x & 63;
    const int row = blockIdx.x * 4 + w;
    const float* src = Y + (size_t)row * n;
    const int beg = lane * CH;
    const int len = max(0, min(CH, n - beg));
    float vals[CH]; unsigned keys[CH];
    #pragma unroll
    for (int i = 0; i < CH; ++i)
        if (i < len) { float v = src[beg + i]; vals[i] = v; keys[i] = f2ord(v); }
    wave_select<CH>(keys, vals, len, k, hist[w], Z + (size_t)row * k);
}

// ---------------------------------------------------------------------------
// FC: (64,352) @ (6,352)^T + b
// ---------------------------------------------------------------------------
__global__ __launch_bounds__(192) void fc_kernel(
    const float* __restrict__ Z, const float* __restrict__ Wf,
    const float* __restrict__ bf, float* __restrict__ out)
{
    int g = blockIdx.x * blockDim.x + threadIdx.x;
    if (g >= 64 * 6) return;
    int b = g / 6, c = g % 6;
    float acc = bf[c];
    const float* zr = Z + b * 352;
    const float* wr = Wf + c * 352;
    for (int i = 0; i < 352; ++i) acc += zr[i] * wr[i];
    out[g] = acc;
}

extern "C" void kernel_launch(void* const* d_in, const int* in_sizes, int n_in,
                              void* d_out, int out_size, void* d_ws, size_t ws_size,
                              hipStream_t stream)
{
    const int*   tokens = (const int*)  d_in[0];
    const float* emb    = (const float*)d_in[1];
    const float* w1     = (const float*)d_in[2];
    const float* b1     = (const float*)d_in[3];
    const float* w2     = (const float*)d_in[4];
    const float* b2     = (const float*)d_in[5];
    const float* w3     = (const float*)d_in[6];
    const float* b3     = (const float*)d_in[7];
    const float* w4     = (const float*)d_in[8];
    const float* b4     = (const float*)d_in[9];
    const float* fcw    = (const float*)d_in[10];
    const float* fcb    = (const float*)d_in[11];
    float* out = (float*)d_out;
    float* ws  = (float*)d_ws;

    // workspace layout (floats):
    //  Z1 [0,        15728640)   64*320*768
    //  Y2 [15728640, 26796032)   64*224*772   (peak ~107 MB, proven to fit)
    //  Z2 [0,         7340032)   64*224*512
    //  Y3 [7340032,  12095488)   64*144*516
    //  Z3 [0,         2359296)   64*144*256
    //  Y4 [2359296,   3812352)   64*88*258
    //  Z4 [3812352,   3834880)   64*88*4
    float* Z1 = ws;
    float* Y2 = ws + 15728640;
    float* Z2 = ws;
    float* Y3 = ws + 7340032;
    float* Z3 = ws;
    float* Y4 = ws + 2359296;
    float* Z4 = ws + 3812352;

    layer1_fused<<<dim3(32, 64), 320, 0, stream>>>(tokens, emb, w1, b1, Z1);

    conv_fold_kernel<10, 14, 5, 256><<<dim3(4, 16, 64), 256, 0, stream>>>(
        Z1, w2, b2, Y2, 320, 768, 772, 224);
    select_kernel<13><<<64 * 224 / 4, 256, 0, stream>>>(Y2, Z2, 772, 512);

    conv_fold_kernel<14, 18, 5, 256><<<dim3(3, 8, 64), 256, 0, stream>>>(
        Z2, w3, b3, Y3, 224, 512, 516, 144);
    select_kernel<9><<<64 * 144 / 4, 256, 0, stream>>>(Y3, Z3, 516, 256);

    conv_fold_kernel<18, 22, 3, 256><<<dim3(2, 4, 64), 256, 0, stream>>>(
        Z3, w4, b4, Y4, 144, 256, 258, 88);
    select_kernel<5><<<64 * 88 / 4, 256, 0, stream>>>(Y4, Z4, 258, 4);

    fc_kernel<<<2, 192, 0, stream>>>(Z4, fcw, fcb, out);
}